// Round 21
// baseline (498.181 us; speedup 1.0000x reference)
//
#include <hip/hip_runtime.h>
#include <math.h>

namespace {

constexpr float INV_SQRT_R = 0.17677669529663689f;

typedef __attribute__((ext_vector_type(8))) __bf16 bf16x8;
typedef __attribute__((ext_vector_type(4))) float f32x4;

static __device__ __forceinline__ f32x4 MF(bf16x8 a, bf16x8 b, f32x4 c) {
    return __builtin_amdgcn_mfma_f32_16x16x32_bf16(a, b, c, 0, 0, 0);
}

// Fragment-ordered layout for MFMA B operands: fidx(n,k) = (k>>5)*(N*32) + n*32 + (k&31).
// Used for mega weights (gwF/w1F/w2F) and qznTF. Topic stays natural (LDS-staged: proven faster).

// ---------------- One-shot weight prep ----------------
__global__ __launch_bounds__(256) void prep_kernel(
    const float* __restrict__ time_u, const float* __restrict__ time_v,
    const float* __restrict__ chan_u, const float* __restrict__ chan_v,
    const float* __restrict__ topic, const float* __restrict__ gate_w,
    const float* __restrict__ w1, const float* __restrict__ w2,
    __bf16* __restrict__ wtime, __bf16* __restrict__ wchan,
    __bf16* __restrict__ topicb, __bf16* __restrict__ topicTb,
    __bf16* __restrict__ gwF, __bf16* __restrict__ w1F, __bf16* __restrict__ w2F)
{
    __shared__ __bf16 tile[32][34];
    const int blk = blockIdx.x;
    const int t = threadIdx.x;
    if (blk < 2048) {
        const int q = blk >> 9, r = blk & 511;
        const float* src; __bf16* dst; int dstOff;
        if (q == 0)      { src = time_u; dst = wtime; dstOff = 0; }
        else if (q == 1) { src = time_v; dst = wtime; dstOff = 65536; }
        else if (q == 2) { src = chan_u; dst = wchan; dstOff = 0; }
        else             { src = chan_v; dst = wchan; dstOff = 65536; }
        int i = (r * 256 + t) * 4;
        float4 v = *(const float4*)(src + i);
        int o = (i >> 16) * 131072 + dstOff + (i & 65535);
        dst[o + 0] = (__bf16)v.x; dst[o + 1] = (__bf16)v.y;
        dst[o + 2] = (__bf16)v.z; dst[o + 3] = (__bf16)v.w;
    } else if (blk < 3072) {
        int i = ((blk - 2048) * 256 + t) * 4;
        float4 v = *(const float4*)(topic + i);
        topicb[i + 0] = (__bf16)v.x; topicb[i + 1] = (__bf16)v.y;
        topicb[i + 2] = (__bf16)v.z; topicb[i + 3] = (__bf16)v.w;
    } else if (blk < 4096) {
        const int idx = blk - 3072;
        const int r0 = (idx & 15) * 32;            // g rows (512)
        const int c0 = ((idx >> 4) & 7) * 32;      // d cols (256)
        const size_t bz = idx >> 7;                // 8 batches
        const float* src = topic + bz * 131072;
        __bf16* dst = topicTb + bz * 131072;
        const int tx = t & 31, ty = t >> 5;
        #pragma unroll
        for (int i = 0; i < 32; i += 8)
            tile[ty + i][tx] = (__bf16)src[(size_t)(r0 + ty + i) * 256 + c0 + tx];
        __syncthreads();
        #pragma unroll
        for (int i = 0; i < 32; i += 8)
            dst[(size_t)(c0 + ty + i) * 512 + r0 + tx] = tile[tx][ty + i];
    } else {
        const int w = (blk - 4096) >> 6;
        const int r = (blk - 4096) & 63;
        const float* src = (w == 0) ? gate_w : ((w == 1) ? w1 : w2);
        __bf16* dstB = (w == 0) ? gwF : ((w == 1) ? w1F : w2F);
        int i = (r * 256 + t) * 4;
        float4 v = *(const float4*)(src + i);
        const int n = i >> 8, k = i & 255;
        __bf16* dst = dstB + (k >> 5) * 8192 + n * 32 + (k & 31);
        dst[0] = (__bf16)v.x; dst[1] = (__bf16)v.y; dst[2] = (__bf16)v.z; dst[3] = (__bf16)v.w;
    }
}

// ---------------- LayerNorm over last dim (256), fp32 in, bf16 out ----------------
__global__ __launch_bounds__(256) void ln_kernel(
    const float* __restrict__ x, const float* __restrict__ sc,
    const float* __restrict__ bi, __bf16* __restrict__ y)
{
    const size_t row = blockIdx.x;
    const int t = threadIdx.x;
    const float v = x[row * 256 + t];
    float s = v, s2 = v * v;
    #pragma unroll
    for (int o = 32; o > 0; o >>= 1) {
        s  += __shfl_xor(s, o);
        s2 += __shfl_xor(s2, o);
    }
    __shared__ float ps[4], ps2[4];
    if ((t & 63) == 0) { ps[t >> 6] = s; ps2[t >> 6] = s2; }
    __syncthreads();
    const float S  = ps[0] + ps[1] + ps[2] + ps[3];
    const float S2 = ps2[0] + ps2[1] + ps2[2] + ps2[3];
    const float mean = S * (1.0f / 256.0f);
    const float var  = S2 * (1.0f / 256.0f) - mean * mean;
    const float inv  = 1.0f / sqrtf(var + 1e-5f);
    y[row * 256 + t] = (__bf16)((v - mean) * inv * sc[t] + bi[t]);
}

// ---------------- qzn -> qznT in fragment order (per bc) ----------------
__global__ __launch_bounds__(256) void tpose_frag_kernel(
    const __bf16* __restrict__ src, __bf16* __restrict__ dst)
{
    const size_t bz = blockIdx.z;
    src += bz * 65536;
    dst += bz * 65536;
    __shared__ __bf16 tile[32][34];
    const int r0 = blockIdx.x * 32, c0 = blockIdx.y * 32;
    const int tx = threadIdx.x & 31, ty = threadIdx.x >> 5;
    #pragma unroll
    for (int i = 0; i < 32; i += 8)
        tile[ty + i][tx] = src[(size_t)(r0 + ty + i) * 256 + c0 + tx];
    __syncthreads();
    #pragma unroll
    for (int i = 0; i < 32; i += 8)
        dst[(r0 >> 5) * 8192 + (c0 + ty + i) * 32 + tx] = tile[tx][ty + i];
}

// ---------------- MFMA bf16 GEMM: merged time+chan projections ----------------
// blockIdx.z in [0,16): z<8 -> time proj (B=wtime, C=qu_t), z>=8 -> chan proj (B=wchan, C=quc).
// Homogeneous resources/duration per block; same proven inner loop.
__global__ __launch_bounds__(256) void mgemm2_kernel(
    const __bf16* __restrict__ A,
    const __bf16* __restrict__ Bt, __bf16* __restrict__ Ct,
    const __bf16* __restrict__ Bc, __bf16* __restrict__ Cc)
{
    const int z = blockIdx.z;
    const int bb = z & 7;
    const bool isChan = (z >= 8);
    const __bf16* Bm = isChan ? Bc : Bt;
    __bf16* Cout = isChan ? Cc : Ct;
    const size_t s_c = isChan ? 32 : 65536;
    const size_t s_p = isChan ? 8192 : 32;
    const size_t s_h = isChan ? 1024 : 8192;
    const int m0 = blockIdx.x * 64;
    const int n0 = blockIdx.y * 256;
    const __bf16* Ab = A + (size_t)bb * 2097152;
    const __bf16* Bb = Bm + (size_t)bb * 131072;
    __shared__ __align__(16) __bf16 As[64][40];
    __shared__ __align__(16) __bf16 Bs[256][40];
    const int t = threadIdx.x;
    const int lane = t & 63;
    const int wid = t >> 6;
    const int l15 = lane & 15, lg = lane >> 4;

    f32x4 acc[4][4] = {};

    for (int k0 = 0; k0 < 256; k0 += 32) {
        {
            const int row = t >> 2, k8 = (t & 3) << 3;
            *(bf16x8*)&As[row][k8] = *(const bf16x8*)(Ab + (size_t)(m0 + row) * 256 + k0 + k8);
        }
        #pragma unroll
        for (int s = 0; s < 4; ++s) {
            const int slot = s * 256 + t;
            const int row = slot >> 2, k8 = (slot & 3) << 3;
            *(bf16x8*)&Bs[row][k8] = *(const bf16x8*)(Bb + (size_t)(n0 + row) * 256 + k0 + k8);
        }
        __syncthreads();
        bf16x8 af[4], bfr[4];
        #pragma unroll
        for (int i = 0; i < 4; ++i)
            af[i] = *(const bf16x8*)&As[i * 16 + l15][lg * 8];
        #pragma unroll
        for (int j = 0; j < 4; ++j)
            bfr[j] = *(const bf16x8*)&Bs[wid * 64 + j * 16 + l15][lg * 8];
        #pragma unroll
        for (int i = 0; i < 4; ++i)
            #pragma unroll
            for (int j = 0; j < 4; ++j)
                acc[i][j] = MF(af[i], bfr[j], acc[i][j]);
        __syncthreads();
    }

    #pragma unroll
    for (int j = 0; j < 4; ++j) {
        const int n = n0 + wid * 64 + j * 16 + l15;
        const size_t offn = (size_t)(n >> 8) * 16777216 + (size_t)((n >> 5) & 7) * s_h + (n & 31);
        #pragma unroll
        for (int i = 0; i < 4; ++i) {
            #pragma unroll
            for (int r = 0; r < 4; ++r) {
                const int m = m0 + i * 16 + lg * 4 + r;
                const size_t off = (size_t)bb * 2097152 + (size_t)(m >> 8) * s_c
                                 + (size_t)(m & 255) * s_p + offn;
                Cout[off] = (__bf16)acc[i][j][r];
            }
        }
    }
}

// ---------------- Fused time attention + PV; GEMM2 B direct from frag qznT ----------------
__global__ __launch_bounds__(256) void time_attn_mt_kernel(
    const __bf16* __restrict__ qu, const __bf16* __restrict__ qv,
    const __bf16* __restrict__ qznTF, __bf16* __restrict__ m_t)
{
    const int bc = blockIdx.x;
    const int p0 = blockIdx.y * 64;
    const __bf16* quB = qu + (size_t)bc * 65536;
    const __bf16* qvB = qv + (size_t)bc * 65536;
    const __bf16* BTF = qznTF + (size_t)bc * 65536;
    __shared__ __align__(16) __bf16 R1[16896];   // A: Us@0 [64][40], Vs@2560 [256][40]; B: aL [64][264]
    __bf16* Us  = R1;
    __bf16* Vs  = R1 + 2560;
    __bf16* aL  = R1;
    const int t = threadIdx.x;
    const int lane = t & 63;
    const int wid = t >> 6;
    const int l15 = lane & 15, lg = lane >> 4;

    f32x4 acc[16] = {};

    for (int h = 0; h < 8; ++h) {
        const __bf16* quH = quB + h * 8192;
        const __bf16* qvH = qvB + h * 8192;
        __syncthreads();
        {
            const int row = t >> 2, k8 = (t & 3) << 3;
            *(bf16x8*)&Us[row * 40 + k8] = *(const bf16x8*)(quH + (size_t)(p0 + row) * 32 + k8);
        }
        #pragma unroll
        for (int i = 0; i < 4; ++i) {
            const int slot = i * 256 + t;
            const int row = slot >> 2, k8 = (slot & 3) << 3;
            *(bf16x8*)&Vs[row * 40 + k8] = *(const bf16x8*)(qvH + (size_t)row * 32 + k8);
        }
        __syncthreads();

        f32x4 s[16];
        bf16x8 a = *(const bf16x8*)&Us[(wid * 16 + l15) * 40 + lg * 8];
        #pragma unroll
        for (int j = 0; j < 16; ++j) {
            bf16x8 bfr = *(const bf16x8*)&Vs[(j * 16 + l15) * 40 + lg * 8];
            s[j] = MF(a, bfr, (f32x4){0.f, 0.f, 0.f, 0.f});
        }

        #pragma unroll
        for (int r = 0; r < 4; ++r) {
            float e[16];
            float sum = 0.0f;
            #pragma unroll
            for (int j = 0; j < 16; ++j) {
                e[j] = __expf(s[j][r] * INV_SQRT_R);
                sum += e[j];
            }
            sum += __shfl_xor(sum, 1);
            sum += __shfl_xor(sum, 2);
            sum += __shfl_xor(sum, 4);
            sum += __shfl_xor(sum, 8);
            const float inv = 0.125f / sum;
            #pragma unroll
            for (int j = 0; j < 16; ++j) acc[j][r] += e[j] * inv;
        }
    }

    __syncthreads();
    #pragma unroll
    for (int r = 0; r < 4; ++r) {
        const int row = wid * 16 + lg * 4 + r;
        #pragma unroll
        for (int j = 0; j < 16; ++j)
            aL[row * 264 + j * 16 + l15] = (__bf16)acc[j][r];
    }
    __syncthreads();

    // GEMM2: m_t[p][d] = Abar[p][q] @ qznT[d][q], K=256; B direct (frag, barrier-free)
    f32x4 acc2[4][4] = {};
    #pragma unroll
    for (int k0 = 0; k0 < 256; k0 += 32) {
        bf16x8 af[4], bfr[4];
        #pragma unroll
        for (int i = 0; i < 4; ++i)
            af[i] = *(const bf16x8*)&aL[(i * 16 + l15) * 264 + k0 + lg * 8];
        #pragma unroll
        for (int j = 0; j < 4; ++j)
            bfr[j] = *(const bf16x8*)(BTF + (k0 >> 5) * 8192 + (wid * 64 + j * 16 + l15) * 32 + lg * 8);
        #pragma unroll
        for (int i = 0; i < 4; ++i)
            #pragma unroll
            for (int j = 0; j < 4; ++j)
                acc2[i][j] = MF(af[i], bfr[j], acc2[i][j]);
    }
    #pragma unroll
    for (int i = 0; i < 4; ++i)
        #pragma unroll
        for (int j = 0; j < 4; ++j) {
            const int d = wid * 64 + j * 16 + l15;
            #pragma unroll
            for (int r = 0; r < 4; ++r) {
                const int p = p0 + i * 16 + lg * 4 + r;
                m_t[(size_t)bc * 65536 + (size_t)p * 256 + d] = (__bf16)acc2[i][j][r];
            }
        }
}

// ---------------- Fused channel attention + PV -> m_c (bf16) ----------------
__global__ __launch_bounds__(256) void chan_fused_kernel(
    const __bf16* __restrict__ quc, const __bf16* __restrict__ qvc,
    const __bf16* __restrict__ qzn, __bf16* __restrict__ m_c)
{
    const int bp = blockIdx.x;
    const int b = bp >> 8, p = bp & 255;
    const __bf16* quB = quc + (size_t)bp * 8192;
    const __bf16* qvB = qvc + (size_t)bp * 8192;
    __shared__ __align__(16) __bf16 QU[20480];
    __shared__ float ab[32 * 33];
    __bf16* qus = QU;
    __bf16* qvs = QU + 10240;
    const int t = threadIdx.x;

    float btr[32];
    #pragma unroll
    for (int f = 0; f < 32; ++f)
        btr[f] = (float)qzn[((size_t)(b * 32 + f) * 256 + p) * 256 + t];

    #pragma unroll
    for (int i = 0; i < 4; ++i) {
        int fi = i * 256 + t;
        int e = fi << 3;
        int h = e >> 10, cc = (e >> 5) & 31, r = e & 31;
        int base = (h * 32 + cc) * 40 + r;
        *(bf16x8*)&qus[base] = *(const bf16x8*)(quB + e);
        *(bf16x8*)&qvs[base] = *(const bf16x8*)(qvB + e);
    }
    __syncthreads();
    const int c = t >> 3, j = t & 7;
    float acc[4] = {0.f, 0.f, 0.f, 0.f};
    for (int h = 0; h < 8; ++h) {
        float qur[32];
        #pragma unroll
        for (int u = 0; u < 4; ++u) {
            bf16x8 q8 = *(const bf16x8*)&qus[(h * 32 + c) * 40 + u * 8];
            #pragma unroll
            for (int e2 = 0; e2 < 8; ++e2) qur[u * 8 + e2] = (float)q8[e2];
        }
        float s[4];
        #pragma unroll
        for (int jj = 0; jj < 4; ++jj) {
            int f = j * 4 + jj;
            float a = 0.f;
            #pragma unroll
            for (int u = 0; u < 4; ++u) {
                bf16x8 v8 = *(const bf16x8*)&qvs[(h * 32 + f) * 40 + u * 8];
                #pragma unroll
                for (int e2 = 0; e2 < 8; ++e2) a += qur[u * 8 + e2] * (float)v8[e2];
            }
            s[jj] = a * INV_SQRT_R;
        }
        float mx = fmaxf(fmaxf(s[0], s[1]), fmaxf(s[2], s[3]));
        mx = fmaxf(mx, __shfl_xor(mx, 1));
        mx = fmaxf(mx, __shfl_xor(mx, 2));
        mx = fmaxf(mx, __shfl_xor(mx, 4));
        float e0x = __expf(s[0] - mx), e1x = __expf(s[1] - mx);
        float e2x = __expf(s[2] - mx), e3x = __expf(s[3] - mx);
        float sum = e0x + e1x + e2x + e3x;
        sum += __shfl_xor(sum, 1);
        sum += __shfl_xor(sum, 2);
        sum += __shfl_xor(sum, 4);
        float inv = 0.125f / sum;
        acc[0] += e0x * inv; acc[1] += e1x * inv; acc[2] += e2x * inv; acc[3] += e3x * inv;
    }
    #pragma unroll
    for (int jj = 0; jj < 4; ++jj) ab[c * 33 + j * 4 + jj] = acc[jj];
    __syncthreads();
    #pragma unroll 2
    for (int c2 = 0; c2 < 32; c2 += 2) {
        float a0 = 0.f, a1 = 0.f;
        #pragma unroll
        for (int f = 0; f < 32; ++f) {
            float v = btr[f];
            a0 += ab[c2 * 33 + f] * v;
            a1 += ab[(c2 + 1) * 33 + f] * v;
        }
        size_t off = ((size_t)(b * 32 + c2) * 256 + p) * 256 + t;
        m_c[off] = (__bf16)a0;
        m_c[off + 65536] = (__bf16)a1;
    }
}

// ---------------- Fused topic factor (LDS-staged, proven) ----------------
__global__ __launch_bounds__(256, 2) void topic_fused_kernel(
    const __bf16* __restrict__ qzn, const __bf16* __restrict__ topicb,
    const __bf16* __restrict__ topicTb, __bf16* __restrict__ m_g)
{
    const int bb = blockIdx.z;
    const int m0 = blockIdx.x * 32;
    const __bf16* Ab = qzn + (size_t)bb * 2097152;
    const __bf16* B1 = topicb + (size_t)bb * 131072;
    const __bf16* B2 = topicTb + (size_t)bb * 131072;
    __shared__ __align__(16) __bf16 As[32][40];
    __shared__ __align__(16) __bf16 Bs[512][40];
    __shared__ __align__(16) __bf16 Ps[32][520];
    __shared__ float rsInv[32];
    const int t = threadIdx.x;
    const int lane = t & 63, wid = t >> 6;
    const int l15 = lane & 15, lg = lane >> 4;

    f32x4 acc[2][8] = {};
    for (int k0 = 0; k0 < 256; k0 += 32) {
        if (t < 128) {
            const int row = t >> 2, k8 = (t & 3) << 3;
            *(bf16x8*)&As[row][k8] = *(const bf16x8*)(Ab + (size_t)(m0 + row) * 256 + k0 + k8);
        }
        #pragma unroll
        for (int s = 0; s < 8; ++s) {
            const int slot = s * 256 + t;
            const int row = slot >> 2, k8 = (slot & 3) << 3;
            *(bf16x8*)&Bs[row][k8] = *(const bf16x8*)(B1 + (size_t)row * 256 + k0 + k8);
        }
        __syncthreads();
        bf16x8 af0 = *(const bf16x8*)&As[l15][lg * 8];
        bf16x8 af1 = *(const bf16x8*)&As[16 + l15][lg * 8];
        #pragma unroll
        for (int j = 0; j < 8; ++j) {
            bf16x8 b8 = *(const bf16x8*)&Bs[wid * 128 + j * 16 + l15][lg * 8];
            acc[0][j] = MF(af0, b8, acc[0][j]);
            acc[1][j] = MF(af1, b8, acc[1][j]);
        }
        __syncthreads();
    }
    #pragma unroll
    for (int i = 0; i < 2; ++i)
        #pragma unroll
        for (int j = 0; j < 8; ++j) {
            const int n = wid * 128 + j * 16 + l15;
            #pragma unroll
            for (int r = 0; r < 4; ++r)
                Ps[i * 16 + lg * 4 + r][n] = (__bf16)fmaxf(acc[i][j][r], 0.0f);
        }
    __syncthreads();
    {
        const int row = t >> 3, seg = t & 7;
        float s = 0.0f;
        #pragma unroll
        for (int u = 0; u < 8; ++u) {
            bf16x8 v = *(const bf16x8*)&Ps[row][seg * 64 + u * 8];
            #pragma unroll
            for (int e = 0; e < 8; ++e) s += (float)v[e];
        }
        s += __shfl_xor(s, 1);
        s += __shfl_xor(s, 2);
        s += __shfl_xor(s, 4);
        if (seg == 0) rsInv[row] = 1.0f / fmaxf(s, 1e-6f);
    }
    __syncthreads();
    f32x4 acc2[2][4] = {};
    for (int k0 = 0; k0 < 512; k0 += 32) {
        #pragma unroll
        for (int s = 0; s < 4; ++s) {
            const int slot = s * 256 + t;
            const int row = slot >> 2, k8 = (slot & 3) << 3;
            *(bf16x8*)&Bs[row][k8] = *(const bf16x8*)(B2 + (size_t)row * 512 + k0 + k8);
        }
        __syncthreads();
        bf16x8 af0 = *(const bf16x8*)&Ps[l15][k0 + lg * 8];
        bf16x8 af1 = *(const bf16x8*)&Ps[16 + l15][k0 + lg * 8];
        #pragma unroll
        for (int j = 0; j < 4; ++j) {
            bf16x8 b8 = *(const bf16x8*)&Bs[wid * 64 + j * 16 + l15][lg * 8];
            acc2[0][j] = MF(af0, b8, acc2[0][j]);
            acc2[1][j] = MF(af1, b8, acc2[1][j]);
        }
        __syncthreads();
    }
    #pragma unroll
    for (int i = 0; i < 2; ++i)
        #pragma unroll
        for (int j = 0; j < 4; ++j) {
            const int n = wid * 64 + j * 16 + l15;
            #pragma unroll
            for (int r = 0; r < 4; ++r) {
                const int ml = i * 16 + lg * 4 + r;
                m_g[(size_t)bb * 2097152 + (size_t)(m0 + ml) * 256 + n]
                    = (__bf16)(acc2[i][j][r] * rsInv[ml]);
            }
        }
}

// ---------------- Mega (frag-direct B, barrier-free GEMMs) ----------------
__global__ __launch_bounds__(256) void mega_kernel(
    const float* __restrict__ qz, const float* __restrict__ unary,
    const __bf16* __restrict__ m_t, const __bf16* __restrict__ m_c,
    const __bf16* __restrict__ m_g,
    const __bf16* __restrict__ gwF, const float* __restrict__ gate_b,
    const __bf16* __restrict__ w1F, const float* __restrict__ b1,
    const __bf16* __restrict__ w2F, const float* __restrict__ b2,
    const float* __restrict__ nsc, const float* __restrict__ nbi,
    float* __restrict__ outp)
{
    const int m0 = blockIdx.x * 64;
    __shared__ __align__(16) __bf16 hL[64][264];
    __shared__ float lnp[64][8];
    const int t = threadIdx.x;
    const int lane = t & 63, wid = t >> 6;
    const int l15 = lane & 15, lg = lane >> 4;

    #pragma unroll
    for (int s = 0; s < 8; ++s) {
        const int slot = s * 256 + t;
        const int row = slot >> 5;
        const int k8 = (slot & 31) << 3;
        const float* src = qz + (size_t)(m0 + row) * 256 + k8;
        float4 v0 = *(const float4*)src;
        float4 v1 = *(const float4*)(src + 4);
        bf16x8 pk;
        pk[0] = (__bf16)v0.x; pk[1] = (__bf16)v0.y; pk[2] = (__bf16)v0.z; pk[3] = (__bf16)v0.w;
        pk[4] = (__bf16)v1.x; pk[5] = (__bf16)v1.y; pk[6] = (__bf16)v1.z; pk[7] = (__bf16)v1.w;
        *(bf16x8*)&hL[row][k8] = pk;
    }
    __syncthreads();

    f32x4 acc[4][4] = {};
    #pragma unroll
    for (int k0 = 0; k0 < 256; k0 += 32) {
        bf16x8 af[4], bfr[4];
        #pragma unroll
        for (int i = 0; i < 4; ++i) af[i] = *(const bf16x8*)&hL[i * 16 + l15][k0 + lg * 8];
        #pragma unroll
        for (int j = 0; j < 4; ++j)
            bfr[j] = *(const bf16x8*)(gwF + (k0 >> 5) * 8192 + (wid * 64 + j * 16 + l15) * 32 + lg * 8);
        #pragma unroll
        for (int i = 0; i < 4; ++i)
            #pragma unroll
            for (int j = 0; j < 4; ++j)
                acc[i][j] = MF(af[i], bfr[j], acc[i][j]);
    }

    f32x4 z2[4][4];
    #pragma unroll
    for (int i = 0; i < 4; ++i) {
        #pragma unroll
        for (int r = 0; r < 4; ++r) {
            const int rr = i * 16 + lg * 4 + r;
            float s = 0.0f, s2 = 0.0f;
            #pragma unroll
            for (int j = 0; j < 4; ++j) {
                const int n = wid * 64 + j * 16 + l15;
                const size_t off = (size_t)(m0 + rr) * 256 + n;
                float g = 1.0f / (1.0f + __expf(-(acc[i][j][r] + gate_b[n])));
                float rest = unary[off] + (float)m_t[off] + (float)m_c[off] + (float)m_g[off];
                float v = g * (float)hL[rr][n] + (1.0f - g) * rest;
                z2[i][j][r] = v;
                s += v; s2 += v * v;
            }
            s  += __shfl_xor(s, 1);  s  += __shfl_xor(s, 2);
            s  += __shfl_xor(s, 4);  s  += __shfl_xor(s, 8);
            s2 += __shfl_xor(s2, 1); s2 += __shfl_xor(s2, 2);
            s2 += __shfl_xor(s2, 4); s2 += __shfl_xor(s2, 8);
            if (l15 == 0) {
                lnp[rr][wid * 2 + 0] = s;
                lnp[rr][wid * 2 + 1] = s2;
            }
        }
    }
    __syncthreads();
    #pragma unroll
    for (int i = 0; i < 4; ++i) {
        #pragma unroll
        for (int r = 0; r < 4; ++r) {
            const int rr = i * 16 + lg * 4 + r;
            float S  = lnp[rr][0] + lnp[rr][2] + lnp[rr][4] + lnp[rr][6];
            float S2 = lnp[rr][1] + lnp[rr][3] + lnp[rr][5] + lnp[rr][7];
            float mean = S * (1.0f / 256.0f);
            float var  = S2 * (1.0f / 256.0f) - mean * mean;
            float inv  = 1.0f / sqrtf(var + 1e-5f);
            #pragma unroll
            for (int j = 0; j < 4; ++j) {
                const int n = wid * 64 + j * 16 + l15;
                hL[rr][n] = (__bf16)((z2[i][j][r] - mean) * inv * nsc[n] + nbi[n]);
            }
        }
    }
    __syncthreads();

    f32x4 acc2[4][4] = {};
    #pragma unroll
    for (int k0 = 0; k0 < 256; k0 += 32) {
        bf16x8 af[4], bfr[4];
        #pragma unroll
        for (int i = 0; i < 4; ++i) af[i] = *(const bf16x8*)&hL[i * 16 + l15][k0 + lg * 8];
        #pragma unroll
        for (int j = 0; j < 4; ++j)
            bfr[j] = *(const bf16x8*)(w1F + (k0 >> 5) * 8192 + (wid * 64 + j * 16 + l15) * 32 + lg * 8);
        #pragma unroll
        for (int i = 0; i < 4; ++i)
            #pragma unroll
            for (int j = 0; j < 4; ++j)
                acc2[i][j] = MF(af[i], bfr[j], acc2[i][j]);
    }
    __syncthreads();
    #pragma unroll
    for (int i = 0; i < 4; ++i)
        #pragma unroll
        for (int j = 0; j < 4; ++j) {
            const int n = wid * 64 + j * 16 + l15;
            const float bn = b1[n];
            #pragma unroll
            for (int r = 0; r < 4; ++r) {
                float x = acc2[i][j][r] + bn;
                hL[i * 16 + lg * 4 + r][n] = (__bf16)(0.5f * x * (1.0f + erff(x * 0.7071067811865475f)));
            }
        }
    __syncthreads();

    f32x4 acc3[4][4] = {};
    #pragma unroll
    for (int k0 = 0; k0 < 256; k0 += 32) {
        bf16x8 af[4], bfr[4];
        #pragma unroll
        for (int i = 0; i < 4; ++i) af[i] = *(const bf16x8*)&hL[i * 16 + l15][k0 + lg * 8];
        #pragma unroll
        for (int j = 0; j < 4; ++j)
            bfr[j] = *(const bf16x8*)(w2F + (k0 >> 5) * 8192 + (wid * 64 + j * 16 + l15) * 32 + lg * 8);
        #pragma unroll
        for (int i = 0; i < 4; ++i)
            #pragma unroll
            for (int j = 0; j < 4; ++j)
                acc3[i][j] = MF(af[i], bfr[j], acc3[i][j]);
    }
    #pragma unroll
    for (int i = 0; i < 4; ++i)
        #pragma unroll
        for (int j = 0; j < 4; ++j) {
            const int n = wid * 64 + j * 16 + l15;
            const float bn = b2[n];
            #pragma unroll
            for (int r = 0; r < 4; ++r) {
                const size_t off = (size_t)(m0 + i * 16 + lg * 4 + r) * 256 + n;
                outp[off] = z2[i][j][r] + acc3[i][j][r] + bn;
            }
        }
}

} // namespace

extern "C" void kernel_launch(void* const* d_in, const int* in_sizes, int n_in,
                              void* d_out, int out_size, void* d_ws, size_t ws_size,
                              hipStream_t stream)
{
    (void)in_sizes; (void)n_in; (void)out_size; (void)ws_size;
    const float* qz     = (const float*)d_in[0];
    const float* unary  = (const float*)d_in[1];
    const float* time_u = (const float*)d_in[2];
    const float* time_v = (const float*)d_in[3];
    const float* chan_u = (const float*)d_in[4];
    const float* chan_v = (const float*)d_in[5];
    const float* topic  = (const float*)d_in[6];
    const float* nsc    = (const float*)d_in[7];
    const float* nbi    = (const float*)d_in[8];
    const float* gate_w = (const float*)d_in[9];
    const float* gate_b = (const float*)d_in[10];
    const float* w1     = (const float*)d_in[11];
    const float* b1     = (const float*)d_in[12];
    const float* w2     = (const float*)d_in[13];
    const float* b2     = (const float*)d_in[14];

    // Memory map (192MB d_ws + d_out scratch):
    //  A.lo [0,32MB):   qzn_b (live through topic_fused)
    //  A.hi [32,64MB):  weight pool
    //  Blo [64,96MB):   qu_t -> m_g
    //  Bhi [96,128MB):  qv_t
    //  C1  [128,160MB): qznTF -> m_c
    //  C2  [160,192MB): m_t
    //  d_out:           qu_c|qv_c (bf16, consumed by chan_fused) -> final fp32 out
    char* base = (char*)d_ws;
    __bf16* qzn_b  = (__bf16*)base;
    __bf16* pool   = (__bf16*)(base + (32ull << 20));
    __bf16* wtime  = pool;
    __bf16* wchan  = pool + 1048576;
    __bf16* topicb = pool + 2097152;
    __bf16* topicTb= pool + 3145728;
    __bf16* gwF    = pool + 4194304;
    __bf16* w1F    = pool + 4259840;
    __bf16* w2F    = pool + 4325376;
    __bf16* Blo    = (__bf16*)(base + (64ull << 20));
    __bf16* Bhi    = (__bf16*)(base + (96ull << 20));
    __bf16* qu_t   = Blo;
    __bf16* qv_t   = Bhi;
    __bf16* m_g    = Blo;
    __bf16* qznTF  = (__bf16*)(base + (128ull << 20));
    __bf16* m_c    = qznTF;
    __bf16* m_t    = (__bf16*)(base + (160ull << 20));
    __bf16* quc    = (__bf16*)d_out;   // chan proj output scratch (dead before mega writes)
    float*  OUTF   = (float*)d_out;

    dim3 blk(256);

    // 0) one-shot weight prep
    prep_kernel<<<4288, blk, 0, stream>>>(
        time_u, time_v, chan_u, chan_v, topic, gate_w, w1, w2,
        wtime, wchan, topicb, topicTb, gwF, w1F, w2F);

    // 1) qz_n = LN(qz) -> qzn_b ; qznTF (frag) -> C1
    ln_kernel<<<65536, blk, 0, stream>>>(qz, nsc, nbi, qzn_b);
    tpose_frag_kernel<<<dim3(8, 8, 256), blk, 0, stream>>>(qzn_b, qznTF);

    // 2) MERGED projections: z<8 time -> qu_t|qv_t (Blo|Bhi), z>=8 chan -> quc (d_out)
    mgemm2_kernel<<<dim3(128, 2, 16), blk, 0, stream>>>(
        qzn_b, wtime, qu_t, wchan, quc);

    // 3) fused time attention + PV -> m_t (C2)
    time_attn_mt_kernel<<<dim3(256, 4), blk, 0, stream>>>(qu_t, qv_t, qznTF, m_t);

    // 4) fused channel attention + PV -> m_c (C1; qznTF dead)
    chan_fused_kernel<<<2048, blk, 0, stream>>>(quc, quc + 16777216, qzn_b, m_c);

    // 5) fused topic factor -> m_g (Blo; qu_t dead)
    topic_fused_kernel<<<dim3(256, 1, 8), blk, 0, stream>>>(qzn_b, topicb, topicTb, m_g);

    // 6) mega: qz-cvt + gate + combine + LN + MLP + residual -> d_out (fp32)
    mega_kernel<<<1024, blk, 0, stream>>>(
        qz, unary, m_t, m_c, m_g,
        gwF, gate_b, w1F, b1, w2F, b2, nsc, nbi, OUTF);
}

// Round 22
// 482.790 us; speedup vs baseline: 1.0319x; 1.0319x over previous
//
#include <hip/hip_runtime.h>
#include <math.h>

namespace {

constexpr float INV_SQRT_R = 0.17677669529663689f;

typedef __attribute__((ext_vector_type(8))) __bf16 bf16x8;
typedef __attribute__((ext_vector_type(4))) float f32x4;

static __device__ __forceinline__ f32x4 MF(bf16x8 a, bf16x8 b, f32x4 c) {
    return __builtin_amdgcn_mfma_f32_16x16x32_bf16(a, b, c, 0, 0, 0);
}

// Fragment-ordered layout for MFMA B operands: fidx(n,k) = (k>>5)*(N*32) + n*32 + (k&31).
// Used for mega weights (gwF/w1F/w2F) and qznTF. Topic stays natural (LDS-staged: proven faster).

// ---------------- One-shot weight prep ----------------
__global__ __launch_bounds__(256) void prep_kernel(
    const float* __restrict__ time_u, const float* __restrict__ time_v,
    const float* __restrict__ chan_u, const float* __restrict__ chan_v,
    const float* __restrict__ topic, const float* __restrict__ gate_w,
    const float* __restrict__ w1, const float* __restrict__ w2,
    __bf16* __restrict__ wtime, __bf16* __restrict__ wchan,
    __bf16* __restrict__ topicb, __bf16* __restrict__ topicTb,
    __bf16* __restrict__ gwF, __bf16* __restrict__ w1F, __bf16* __restrict__ w2F)
{
    __shared__ __bf16 tile[32][34];
    const int blk = blockIdx.x;
    const int t = threadIdx.x;
    if (blk < 2048) {
        const int q = blk >> 9, r = blk & 511;
        const float* src; __bf16* dst; int dstOff;
        if (q == 0)      { src = time_u; dst = wtime; dstOff = 0; }
        else if (q == 1) { src = time_v; dst = wtime; dstOff = 65536; }
        else if (q == 2) { src = chan_u; dst = wchan; dstOff = 0; }
        else             { src = chan_v; dst = wchan; dstOff = 65536; }
        int i = (r * 256 + t) * 4;
        float4 v = *(const float4*)(src + i);
        int o = (i >> 16) * 131072 + dstOff + (i & 65535);
        dst[o + 0] = (__bf16)v.x; dst[o + 1] = (__bf16)v.y;
        dst[o + 2] = (__bf16)v.z; dst[o + 3] = (__bf16)v.w;
    } else if (blk < 3072) {
        int i = ((blk - 2048) * 256 + t) * 4;
        float4 v = *(const float4*)(topic + i);
        topicb[i + 0] = (__bf16)v.x; topicb[i + 1] = (__bf16)v.y;
        topicb[i + 2] = (__bf16)v.z; topicb[i + 3] = (__bf16)v.w;
    } else if (blk < 4096) {
        const int idx = blk - 3072;
        const int r0 = (idx & 15) * 32;            // g rows (512)
        const int c0 = ((idx >> 4) & 7) * 32;      // d cols (256)
        const size_t bz = idx >> 7;                // 8 batches
        const float* src = topic + bz * 131072;
        __bf16* dst = topicTb + bz * 131072;
        const int tx = t & 31, ty = t >> 5;
        #pragma unroll
        for (int i = 0; i < 32; i += 8)
            tile[ty + i][tx] = (__bf16)src[(size_t)(r0 + ty + i) * 256 + c0 + tx];
        __syncthreads();
        #pragma unroll
        for (int i = 0; i < 32; i += 8)
            dst[(size_t)(c0 + ty + i) * 512 + r0 + tx] = tile[tx][ty + i];
    } else {
        const int w = (blk - 4096) >> 6;
        const int r = (blk - 4096) & 63;
        const float* src = (w == 0) ? gate_w : ((w == 1) ? w1 : w2);
        __bf16* dstB = (w == 0) ? gwF : ((w == 1) ? w1F : w2F);
        int i = (r * 256 + t) * 4;
        float4 v = *(const float4*)(src + i);
        const int n = i >> 8, k = i & 255;
        __bf16* dst = dstB + (k >> 5) * 8192 + n * 32 + (k & 31);
        dst[0] = (__bf16)v.x; dst[1] = (__bf16)v.y; dst[2] = (__bf16)v.z; dst[3] = (__bf16)v.w;
    }
}

// ---------------- LayerNorm over last dim (256), fp32 in, bf16 out ----------------
__global__ __launch_bounds__(256) void ln_kernel(
    const float* __restrict__ x, const float* __restrict__ sc,
    const float* __restrict__ bi, __bf16* __restrict__ y)
{
    const size_t row = blockIdx.x;
    const int t = threadIdx.x;
    const float v = x[row * 256 + t];
    float s = v, s2 = v * v;
    #pragma unroll
    for (int o = 32; o > 0; o >>= 1) {
        s  += __shfl_xor(s, o);
        s2 += __shfl_xor(s2, o);
    }
    __shared__ float ps[4], ps2[4];
    if ((t & 63) == 0) { ps[t >> 6] = s; ps2[t >> 6] = s2; }
    __syncthreads();
    const float S  = ps[0] + ps[1] + ps[2] + ps[3];
    const float S2 = ps2[0] + ps2[1] + ps2[2] + ps2[3];
    const float mean = S * (1.0f / 256.0f);
    const float var  = S2 * (1.0f / 256.0f) - mean * mean;
    const float inv  = 1.0f / sqrtf(var + 1e-5f);
    y[row * 256 + t] = (__bf16)((v - mean) * inv * sc[t] + bi[t]);
}

// ---------------- qzn -> qznT in fragment order (per bc) ----------------
__global__ __launch_bounds__(256) void tpose_frag_kernel(
    const __bf16* __restrict__ src, __bf16* __restrict__ dst)
{
    const size_t bz = blockIdx.z;
    src += bz * 65536;
    dst += bz * 65536;
    __shared__ __bf16 tile[32][34];
    const int r0 = blockIdx.x * 32, c0 = blockIdx.y * 32;
    const int tx = threadIdx.x & 31, ty = threadIdx.x >> 5;
    #pragma unroll
    for (int i = 0; i < 32; i += 8)
        tile[ty + i][tx] = src[(size_t)(r0 + ty + i) * 256 + c0 + tx];
    __syncthreads();
    #pragma unroll
    for (int i = 0; i < 32; i += 8)
        dst[(r0 >> 5) * 8192 + (c0 + ty + i) * 32 + tx] = tile[tx][ty + i];
}

// ---------------- MFMA bf16 GEMM (projections): proven form ----------------
__global__ __launch_bounds__(256) void mgemm_kernel(
    const __bf16* __restrict__ A, const __bf16* __restrict__ Bm, __bf16* __restrict__ Cout,
    int K, size_t aStride, size_t bStride,
    size_t s_b, size_t s_c, size_t s_p, size_t s_w, size_t s_h)
{
    const int bb = blockIdx.z;
    const int m0 = blockIdx.x * 64;
    const int n0 = blockIdx.y * 256;
    const __bf16* Ab = A + (size_t)bb * aStride;
    const __bf16* Bb = Bm + (size_t)bb * bStride;
    __shared__ __align__(16) __bf16 As[64][40];
    __shared__ __align__(16) __bf16 Bs[256][40];
    const int t = threadIdx.x;
    const int lane = t & 63;
    const int wid = t >> 6;
    const int l15 = lane & 15, lg = lane >> 4;

    f32x4 acc[4][4] = {};

    for (int k0 = 0; k0 < K; k0 += 32) {
        {
            const int row = t >> 2, k8 = (t & 3) << 3;
            *(bf16x8*)&As[row][k8] = *(const bf16x8*)(Ab + (size_t)(m0 + row) * K + k0 + k8);
        }
        #pragma unroll
        for (int s = 0; s < 4; ++s) {
            const int slot = s * 256 + t;
            const int row = slot >> 2, k8 = (slot & 3) << 3;
            *(bf16x8*)&Bs[row][k8] = *(const bf16x8*)(Bb + (size_t)(n0 + row) * K + k0 + k8);
        }
        __syncthreads();
        bf16x8 af[4], bfr[4];
        #pragma unroll
        for (int i = 0; i < 4; ++i)
            af[i] = *(const bf16x8*)&As[i * 16 + l15][lg * 8];
        #pragma unroll
        for (int j = 0; j < 4; ++j)
            bfr[j] = *(const bf16x8*)&Bs[wid * 64 + j * 16 + l15][lg * 8];
        #pragma unroll
        for (int i = 0; i < 4; ++i)
            #pragma unroll
            for (int j = 0; j < 4; ++j)
                acc[i][j] = MF(af[i], bfr[j], acc[i][j]);
        __syncthreads();
    }

    #pragma unroll
    for (int j = 0; j < 4; ++j) {
        const int n = n0 + wid * 64 + j * 16 + l15;
        const size_t offn = (size_t)(n >> 8) * s_w + (size_t)((n >> 5) & 7) * s_h + (n & 31);
        #pragma unroll
        for (int i = 0; i < 4; ++i) {
            #pragma unroll
            for (int r = 0; r < 4; ++r) {
                const int m = m0 + i * 16 + lg * 4 + r;
                const size_t off = (size_t)bb * s_b + (size_t)(m >> 8) * s_c
                                 + (size_t)(m & 255) * s_p + offn;
                Cout[off] = (__bf16)acc[i][j][r];
            }
        }
    }
}

// ---------------- Fused time attention + PV; GEMM2 B direct from frag qznT ----------------
__global__ __launch_bounds__(256) void time_attn_mt_kernel(
    const __bf16* __restrict__ qu, const __bf16* __restrict__ qv,
    const __bf16* __restrict__ qznTF, __bf16* __restrict__ m_t)
{
    const int bc = blockIdx.x;
    const int p0 = blockIdx.y * 64;
    const __bf16* quB = qu + (size_t)bc * 65536;
    const __bf16* qvB = qv + (size_t)bc * 65536;
    const __bf16* BTF = qznTF + (size_t)bc * 65536;
    __shared__ __align__(16) __bf16 R1[16896];   // A: Us@0 [64][40], Vs@2560 [256][40]; B: aL [64][264]
    __bf16* Us  = R1;
    __bf16* Vs  = R1 + 2560;
    __bf16* aL  = R1;
    const int t = threadIdx.x;
    const int lane = t & 63;
    const int wid = t >> 6;
    const int l15 = lane & 15, lg = lane >> 4;

    f32x4 acc[16] = {};

    for (int h = 0; h < 8; ++h) {
        const __bf16* quH = quB + h * 8192;
        const __bf16* qvH = qvB + h * 8192;
        __syncthreads();
        {
            const int row = t >> 2, k8 = (t & 3) << 3;
            *(bf16x8*)&Us[row * 40 + k8] = *(const bf16x8*)(quH + (size_t)(p0 + row) * 32 + k8);
        }
        #pragma unroll
        for (int i = 0; i < 4; ++i) {
            const int slot = i * 256 + t;
            const int row = slot >> 2, k8 = (slot & 3) << 3;
            *(bf16x8*)&Vs[row * 40 + k8] = *(const bf16x8*)(qvH + (size_t)row * 32 + k8);
        }
        __syncthreads();

        f32x4 s[16];
        bf16x8 a = *(const bf16x8*)&Us[(wid * 16 + l15) * 40 + lg * 8];
        #pragma unroll
        for (int j = 0; j < 16; ++j) {
            bf16x8 bfr = *(const bf16x8*)&Vs[(j * 16 + l15) * 40 + lg * 8];
            s[j] = MF(a, bfr, (f32x4){0.f, 0.f, 0.f, 0.f});
        }

        #pragma unroll
        for (int r = 0; r < 4; ++r) {
            float e[16];
            float sum = 0.0f;
            #pragma unroll
            for (int j = 0; j < 16; ++j) {
                e[j] = __expf(s[j][r] * INV_SQRT_R);
                sum += e[j];
            }
            sum += __shfl_xor(sum, 1);
            sum += __shfl_xor(sum, 2);
            sum += __shfl_xor(sum, 4);
            sum += __shfl_xor(sum, 8);
            const float inv = 0.125f / sum;
            #pragma unroll
            for (int j = 0; j < 16; ++j) acc[j][r] += e[j] * inv;
        }
    }

    __syncthreads();
    #pragma unroll
    for (int r = 0; r < 4; ++r) {
        const int row = wid * 16 + lg * 4 + r;
        #pragma unroll
        for (int j = 0; j < 16; ++j)
            aL[row * 264 + j * 16 + l15] = (__bf16)acc[j][r];
    }
    __syncthreads();

    // GEMM2: m_t[p][d] = Abar[p][q] @ qznT[d][q], K=256; B direct (frag, barrier-free)
    f32x4 acc2[4][4] = {};
    #pragma unroll
    for (int k0 = 0; k0 < 256; k0 += 32) {
        bf16x8 af[4], bfr[4];
        #pragma unroll
        for (int i = 0; i < 4; ++i)
            af[i] = *(const bf16x8*)&aL[(i * 16 + l15) * 264 + k0 + lg * 8];
        #pragma unroll
        for (int j = 0; j < 4; ++j)
            bfr[j] = *(const bf16x8*)(BTF + (k0 >> 5) * 8192 + (wid * 64 + j * 16 + l15) * 32 + lg * 8);
        #pragma unroll
        for (int i = 0; i < 4; ++i)
            #pragma unroll
            for (int j = 0; j < 4; ++j)
                acc2[i][j] = MF(af[i], bfr[j], acc2[i][j]);
    }
    #pragma unroll
    for (int i = 0; i < 4; ++i)
        #pragma unroll
        for (int j = 0; j < 4; ++j) {
            const int d = wid * 64 + j * 16 + l15;
            #pragma unroll
            for (int r = 0; r < 4; ++r) {
                const int p = p0 + i * 16 + lg * 4 + r;
                m_t[(size_t)bc * 65536 + (size_t)p * 256 + d] = (__bf16)acc2[i][j][r];
            }
        }
}

// ---------------- Fused channel attention + PV -> m_c (bf16) ----------------
__global__ __launch_bounds__(256) void chan_fused_kernel(
    const __bf16* __restrict__ quc, const __bf16* __restrict__ qvc,
    const __bf16* __restrict__ qzn, __bf16* __restrict__ m_c)
{
    const int bp = blockIdx.x;
    const int b = bp >> 8, p = bp & 255;
    const __bf16* quB = quc + (size_t)bp * 8192;
    const __bf16* qvB = qvc + (size_t)bp * 8192;
    __shared__ __align__(16) __bf16 QU[20480];
    __shared__ float ab[32 * 33];
    __bf16* qus = QU;
    __bf16* qvs = QU + 10240;
    const int t = threadIdx.x;

    float btr[32];
    #pragma unroll
    for (int f = 0; f < 32; ++f)
        btr[f] = (float)qzn[((size_t)(b * 32 + f) * 256 + p) * 256 + t];

    #pragma unroll
    for (int i = 0; i < 4; ++i) {
        int fi = i * 256 + t;
        int e = fi << 3;
        int h = e >> 10, cc = (e >> 5) & 31, r = e & 31;
        int base = (h * 32 + cc) * 40 + r;
        *(bf16x8*)&qus[base] = *(const bf16x8*)(quB + e);
        *(bf16x8*)&qvs[base] = *(const bf16x8*)(qvB + e);
    }
    __syncthreads();
    const int c = t >> 3, j = t & 7;
    float acc[4] = {0.f, 0.f, 0.f, 0.f};
    for (int h = 0; h < 8; ++h) {
        float qur[32];
        #pragma unroll
        for (int u = 0; u < 4; ++u) {
            bf16x8 q8 = *(const bf16x8*)&qus[(h * 32 + c) * 40 + u * 8];
            #pragma unroll
            for (int e2 = 0; e2 < 8; ++e2) qur[u * 8 + e2] = (float)q8[e2];
        }
        float s[4];
        #pragma unroll
        for (int jj = 0; jj < 4; ++jj) {
            int f = j * 4 + jj;
            float a = 0.f;
            #pragma unroll
            for (int u = 0; u < 4; ++u) {
                bf16x8 v8 = *(const bf16x8*)&qvs[(h * 32 + f) * 40 + u * 8];
                #pragma unroll
                for (int e2 = 0; e2 < 8; ++e2) a += qur[u * 8 + e2] * (float)v8[e2];
            }
            s[jj] = a * INV_SQRT_R;
        }
        float mx = fmaxf(fmaxf(s[0], s[1]), fmaxf(s[2], s[3]));
        mx = fmaxf(mx, __shfl_xor(mx, 1));
        mx = fmaxf(mx, __shfl_xor(mx, 2));
        mx = fmaxf(mx, __shfl_xor(mx, 4));
        float e0x = __expf(s[0] - mx), e1x = __expf(s[1] - mx);
        float e2x = __expf(s[2] - mx), e3x = __expf(s[3] - mx);
        float sum = e0x + e1x + e2x + e3x;
        sum += __shfl_xor(sum, 1);
        sum += __shfl_xor(sum, 2);
        sum += __shfl_xor(sum, 4);
        float inv = 0.125f / sum;
        acc[0] += e0x * inv; acc[1] += e1x * inv; acc[2] += e2x * inv; acc[3] += e3x * inv;
    }
    #pragma unroll
    for (int jj = 0; jj < 4; ++jj) ab[c * 33 + j * 4 + jj] = acc[jj];
    __syncthreads();
    #pragma unroll 2
    for (int c2 = 0; c2 < 32; c2 += 2) {
        float a0 = 0.f, a1 = 0.f;
        #pragma unroll
        for (int f = 0; f < 32; ++f) {
            float v = btr[f];
            a0 += ab[c2 * 33 + f] * v;
            a1 += ab[(c2 + 1) * 33 + f] * v;
        }
        size_t off = ((size_t)(b * 32 + c2) * 256 + p) * 256 + t;
        m_c[off] = (__bf16)a0;
        m_c[off + 65536] = (__bf16)a1;
    }
}

// ---------------- Fused topic factor (LDS-staged, proven) ----------------
__global__ __launch_bounds__(256, 2) void topic_fused_kernel(
    const __bf16* __restrict__ qzn, const __bf16* __restrict__ topicb,
    const __bf16* __restrict__ topicTb, __bf16* __restrict__ m_g)
{
    const int bb = blockIdx.z;
    const int m0 = blockIdx.x * 32;
    const __bf16* Ab = qzn + (size_t)bb * 2097152;
    const __bf16* B1 = topicb + (size_t)bb * 131072;
    const __bf16* B2 = topicTb + (size_t)bb * 131072;
    __shared__ __align__(16) __bf16 As[32][40];
    __shared__ __align__(16) __bf16 Bs[512][40];
    __shared__ __align__(16) __bf16 Ps[32][520];
    __shared__ float rsInv[32];
    const int t = threadIdx.x;
    const int lane = t & 63, wid = t >> 6;
    const int l15 = lane & 15, lg = lane >> 4;

    f32x4 acc[2][8] = {};
    for (int k0 = 0; k0 < 256; k0 += 32) {
        if (t < 128) {
            const int row = t >> 2, k8 = (t & 3) << 3;
            *(bf16x8*)&As[row][k8] = *(const bf16x8*)(Ab + (size_t)(m0 + row) * 256 + k0 + k8);
        }
        #pragma unroll
        for (int s = 0; s < 8; ++s) {
            const int slot = s * 256 + t;
            const int row = slot >> 2, k8 = (slot & 3) << 3;
            *(bf16x8*)&Bs[row][k8] = *(const bf16x8*)(B1 + (size_t)row * 256 + k0 + k8);
        }
        __syncthreads();
        bf16x8 af0 = *(const bf16x8*)&As[l15][lg * 8];
        bf16x8 af1 = *(const bf16x8*)&As[16 + l15][lg * 8];
        #pragma unroll
        for (int j = 0; j < 8; ++j) {
            bf16x8 b8 = *(const bf16x8*)&Bs[wid * 128 + j * 16 + l15][lg * 8];
            acc[0][j] = MF(af0, b8, acc[0][j]);
            acc[1][j] = MF(af1, b8, acc[1][j]);
        }
        __syncthreads();
    }
    #pragma unroll
    for (int i = 0; i < 2; ++i)
        #pragma unroll
        for (int j = 0; j < 8; ++j) {
            const int n = wid * 128 + j * 16 + l15;
            #pragma unroll
            for (int r = 0; r < 4; ++r)
                Ps[i * 16 + lg * 4 + r][n] = (__bf16)fmaxf(acc[i][j][r], 0.0f);
        }
    __syncthreads();
    {
        const int row = t >> 3, seg = t & 7;
        float s = 0.0f;
        #pragma unroll
        for (int u = 0; u < 8; ++u) {
            bf16x8 v = *(const bf16x8*)&Ps[row][seg * 64 + u * 8];
            #pragma unroll
            for (int e = 0; e < 8; ++e) s += (float)v[e];
        }
        s += __shfl_xor(s, 1);
        s += __shfl_xor(s, 2);
        s += __shfl_xor(s, 4);
        if (seg == 0) rsInv[row] = 1.0f / fmaxf(s, 1e-6f);
    }
    __syncthreads();
    f32x4 acc2[2][4] = {};
    for (int k0 = 0; k0 < 512; k0 += 32) {
        #pragma unroll
        for (int s = 0; s < 4; ++s) {
            const int slot = s * 256 + t;
            const int row = slot >> 2, k8 = (slot & 3) << 3;
            *(bf16x8*)&Bs[row][k8] = *(const bf16x8*)(B2 + (size_t)row * 512 + k0 + k8);
        }
        __syncthreads();
        bf16x8 af0 = *(const bf16x8*)&Ps[l15][k0 + lg * 8];
        bf16x8 af1 = *(const bf16x8*)&Ps[16 + l15][k0 + lg * 8];
        #pragma unroll
        for (int j = 0; j < 4; ++j) {
            bf16x8 b8 = *(const bf16x8*)&Bs[wid * 64 + j * 16 + l15][lg * 8];
            acc2[0][j] = MF(af0, b8, acc2[0][j]);
            acc2[1][j] = MF(af1, b8, acc2[1][j]);
        }
        __syncthreads();
    }
    #pragma unroll
    for (int i = 0; i < 2; ++i)
        #pragma unroll
        for (int j = 0; j < 4; ++j) {
            const int n = wid * 64 + j * 16 + l15;
            #pragma unroll
            for (int r = 0; r < 4; ++r) {
                const int ml = i * 16 + lg * 4 + r;
                m_g[(size_t)bb * 2097152 + (size_t)(m0 + ml) * 256 + n]
                    = (__bf16)(acc2[i][j][r] * rsInv[ml]);
            }
        }
}

// ---------------- Mega (frag-direct B, barrier-free GEMMs) ----------------
__global__ __launch_bounds__(256) void mega_kernel(
    const float* __restrict__ qz, const float* __restrict__ unary,
    const __bf16* __restrict__ m_t, const __bf16* __restrict__ m_c,
    const __bf16* __restrict__ m_g,
    const __bf16* __restrict__ gwF, const float* __restrict__ gate_b,
    const __bf16* __restrict__ w1F, const float* __restrict__ b1,
    const __bf16* __restrict__ w2F, const float* __restrict__ b2,
    const float* __restrict__ nsc, const float* __restrict__ nbi,
    float* __restrict__ outp)
{
    const int m0 = blockIdx.x * 64;
    __shared__ __align__(16) __bf16 hL[64][264];
    __shared__ float lnp[64][8];
    const int t = threadIdx.x;
    const int lane = t & 63, wid = t >> 6;
    const int l15 = lane & 15, lg = lane >> 4;

    #pragma unroll
    for (int s = 0; s < 8; ++s) {
        const int slot = s * 256 + t;
        const int row = slot >> 5;
        const int k8 = (slot & 31) << 3;
        const float* src = qz + (size_t)(m0 + row) * 256 + k8;
        float4 v0 = *(const float4*)src;
        float4 v1 = *(const float4*)(src + 4);
        bf16x8 pk;
        pk[0] = (__bf16)v0.x; pk[1] = (__bf16)v0.y; pk[2] = (__bf16)v0.z; pk[3] = (__bf16)v0.w;
        pk[4] = (__bf16)v1.x; pk[5] = (__bf16)v1.y; pk[6] = (__bf16)v1.z; pk[7] = (__bf16)v1.w;
        *(bf16x8*)&hL[row][k8] = pk;
    }
    __syncthreads();

    f32x4 acc[4][4] = {};
    #pragma unroll
    for (int k0 = 0; k0 < 256; k0 += 32) {
        bf16x8 af[4], bfr[4];
        #pragma unroll
        for (int i = 0; i < 4; ++i) af[i] = *(const bf16x8*)&hL[i * 16 + l15][k0 + lg * 8];
        #pragma unroll
        for (int j = 0; j < 4; ++j)
            bfr[j] = *(const bf16x8*)(gwF + (k0 >> 5) * 8192 + (wid * 64 + j * 16 + l15) * 32 + lg * 8);
        #pragma unroll
        for (int i = 0; i < 4; ++i)
            #pragma unroll
            for (int j = 0; j < 4; ++j)
                acc[i][j] = MF(af[i], bfr[j], acc[i][j]);
    }

    f32x4 z2[4][4];
    #pragma unroll
    for (int i = 0; i < 4; ++i) {
        #pragma unroll
        for (int r = 0; r < 4; ++r) {
            const int rr = i * 16 + lg * 4 + r;
            float s = 0.0f, s2 = 0.0f;
            #pragma unroll
            for (int j = 0; j < 4; ++j) {
                const int n = wid * 64 + j * 16 + l15;
                const size_t off = (size_t)(m0 + rr) * 256 + n;
                float g = 1.0f / (1.0f + __expf(-(acc[i][j][r] + gate_b[n])));
                float rest = unary[off] + (float)m_t[off] + (float)m_c[off] + (float)m_g[off];
                float v = g * (float)hL[rr][n] + (1.0f - g) * rest;
                z2[i][j][r] = v;
                s += v; s2 += v * v;
            }
            s  += __shfl_xor(s, 1);  s  += __shfl_xor(s, 2);
            s  += __shfl_xor(s, 4);  s  += __shfl_xor(s, 8);
            s2 += __shfl_xor(s2, 1); s2 += __shfl_xor(s2, 2);
            s2 += __shfl_xor(s2, 4); s2 += __shfl_xor(s2, 8);
            if (l15 == 0) {
                lnp[rr][wid * 2 + 0] = s;
                lnp[rr][wid * 2 + 1] = s2;
            }
        }
    }
    __syncthreads();
    #pragma unroll
    for (int i = 0; i < 4; ++i) {
        #pragma unroll
        for (int r = 0; r < 4; ++r) {
            const int rr = i * 16 + lg * 4 + r;
            float S  = lnp[rr][0] + lnp[rr][2] + lnp[rr][4] + lnp[rr][6];
            float S2 = lnp[rr][1] + lnp[rr][3] + lnp[rr][5] + lnp[rr][7];
            float mean = S * (1.0f / 256.0f);
            float var  = S2 * (1.0f / 256.0f) - mean * mean;
            float inv  = 1.0f / sqrtf(var + 1e-5f);
            #pragma unroll
            for (int j = 0; j < 4; ++j) {
                const int n = wid * 64 + j * 16 + l15;
                hL[rr][n] = (__bf16)((z2[i][j][r] - mean) * inv * nsc[n] + nbi[n]);
            }
        }
    }
    __syncthreads();

    f32x4 acc2[4][4] = {};
    #pragma unroll
    for (int k0 = 0; k0 < 256; k0 += 32) {
        bf16x8 af[4], bfr[4];
        #pragma unroll
        for (int i = 0; i < 4; ++i) af[i] = *(const bf16x8*)&hL[i * 16 + l15][k0 + lg * 8];
        #pragma unroll
        for (int j = 0; j < 4; ++j)
            bfr[j] = *(const bf16x8*)(w1F + (k0 >> 5) * 8192 + (wid * 64 + j * 16 + l15) * 32 + lg * 8);
        #pragma unroll
        for (int i = 0; i < 4; ++i)
            #pragma unroll
            for (int j = 0; j < 4; ++j)
                acc2[i][j] = MF(af[i], bfr[j], acc2[i][j]);
    }
    __syncthreads();
    #pragma unroll
    for (int i = 0; i < 4; ++i)
        #pragma unroll
        for (int j = 0; j < 4; ++j) {
            const int n = wid * 64 + j * 16 + l15;
            const float bn = b1[n];
            #pragma unroll
            for (int r = 0; r < 4; ++r) {
                float x = acc2[i][j][r] + bn;
                hL[i * 16 + lg * 4 + r][n] = (__bf16)(0.5f * x * (1.0f + erff(x * 0.7071067811865475f)));
            }
        }
    __syncthreads();

    f32x4 acc3[4][4] = {};
    #pragma unroll
    for (int k0 = 0; k0 < 256; k0 += 32) {
        bf16x8 af[4], bfr[4];
        #pragma unroll
        for (int i = 0; i < 4; ++i) af[i] = *(const bf16x8*)&hL[i * 16 + l15][k0 + lg * 8];
        #pragma unroll
        for (int j = 0; j < 4; ++j)
            bfr[j] = *(const bf16x8*)(w2F + (k0 >> 5) * 8192 + (wid * 64 + j * 16 + l15) * 32 + lg * 8);
        #pragma unroll
        for (int i = 0; i < 4; ++i)
            #pragma unroll
            for (int j = 0; j < 4; ++j)
                acc3[i][j] = MF(af[i], bfr[j], acc3[i][j]);
    }
    #pragma unroll
    for (int i = 0; i < 4; ++i)
        #pragma unroll
        for (int j = 0; j < 4; ++j) {
            const int n = wid * 64 + j * 16 + l15;
            const float bn = b2[n];
            #pragma unroll
            for (int r = 0; r < 4; ++r) {
                const size_t off = (size_t)(m0 + i * 16 + lg * 4 + r) * 256 + n;
                outp[off] = z2[i][j][r] + acc3[i][j][r] + bn;
            }
        }
}

} // namespace

extern "C" void kernel_launch(void* const* d_in, const int* in_sizes, int n_in,
                              void* d_out, int out_size, void* d_ws, size_t ws_size,
                              hipStream_t stream)
{
    (void)in_sizes; (void)n_in; (void)out_size; (void)ws_size;
    const float* qz     = (const float*)d_in[0];
    const float* unary  = (const float*)d_in[1];
    const float* time_u = (const float*)d_in[2];
    const float* time_v = (const float*)d_in[3];
    const float* chan_u = (const float*)d_in[4];
    const float* chan_v = (const float*)d_in[5];
    const float* topic  = (const float*)d_in[6];
    const float* nsc    = (const float*)d_in[7];
    const float* nbi    = (const float*)d_in[8];
    const float* gate_w = (const float*)d_in[9];
    const float* gate_b = (const float*)d_in[10];
    const float* w1     = (const float*)d_in[11];
    const float* b1     = (const float*)d_in[12];
    const float* w2     = (const float*)d_in[13];
    const float* b2     = (const float*)d_in[14];

    // Memory map (192MB d_ws):
    //  A.lo [0,32MB):   qzn_b (live through topic_fused)
    //  A.hi [32,64MB):  weight pool
    //  Blo [64,96MB):   qu_t -> qu_c -> m_g
    //  Bhi [96,128MB):  qv_t -> qv_c
    //  C1  [128,160MB): qznTF -> m_c
    //  C2  [160,192MB): m_t
    char* base = (char*)d_ws;
    __bf16* qzn_b  = (__bf16*)base;
    __bf16* pool   = (__bf16*)(base + (32ull << 20));
    __bf16* wtime  = pool;
    __bf16* wchan  = pool + 1048576;
    __bf16* topicb = pool + 2097152;
    __bf16* topicTb= pool + 3145728;
    __bf16* gwF    = pool + 4194304;
    __bf16* w1F    = pool + 4259840;
    __bf16* w2F    = pool + 4325376;
    __bf16* Blo    = (__bf16*)(base + (64ull << 20));
    __bf16* Bhi    = (__bf16*)(base + (96ull << 20));
    __bf16* qu_t   = Blo;
    __bf16* qv_t   = Bhi;
    __bf16* qu_c   = Blo;
    __bf16* qv_c   = Bhi;
    __bf16* m_g    = Blo;
    __bf16* qznTF  = (__bf16*)(base + (128ull << 20));
    __bf16* m_c    = qznTF;
    __bf16* m_t    = (__bf16*)(base + (160ull << 20));
    float*  OUTF   = (float*)d_out;

    dim3 blk(256);

    // 0) one-shot weight prep
    prep_kernel<<<4288, blk, 0, stream>>>(
        time_u, time_v, chan_u, chan_v, topic, gate_w, w1, w2,
        wtime, wchan, topicb, topicTb, gwF, w1F, w2F);

    // 1) qz_n = LN(qz) -> qzn_b ; qznTF (frag) -> C1
    ln_kernel<<<65536, blk, 0, stream>>>(qz, nsc, nbi, qzn_b);
    tpose_frag_kernel<<<dim3(8, 8, 256), blk, 0, stream>>>(qzn_b, qznTF);

    // 2) time projections (stacked N=512) -> qu_t | qv_t  [b][c][h][p][r]
    mgemm_kernel<<<dim3(128, 2, 8), blk, 0, stream>>>(
        qzn_b, wtime, qu_t, 256, 2097152, 131072,
        2097152, 65536, 32, 16777216, 8192);

    // 3) fused time attention + PV -> m_t (C2)
    time_attn_mt_kernel<<<dim3(256, 4), blk, 0, stream>>>(qu_t, qv_t, qznTF, m_t);

    // 4) channel projections (stacked) -> qu_c | qv_c  [b][p][h][c][r]
    mgemm_kernel<<<dim3(128, 2, 8), blk, 0, stream>>>(
        qzn_b, wchan, qu_c, 256, 2097152, 131072,
        2097152, 32, 8192, 16777216, 1024);

    // 5) fused channel attention + PV -> m_c (C1; qznTF dead)
    chan_fused_kernel<<<2048, blk, 0, stream>>>(qu_c, qv_c, qzn_b, m_c);

    // 6) fused topic factor -> m_g (Blo; qu_c dead)
    topic_fused_kernel<<<dim3(256, 1, 8), blk, 0, stream>>>(qzn_b, topicb, topicTb, m_g);

    // 7) mega: qz-cvt + gate + combine + LN + MLP + residual -> d_out (fp32)
    mega_kernel<<<1024, blk, 0, stream>>>(
        qz, unary, m_t, m_c, m_g,
        gwF, gate_b, w1F, b1, w2F, b2, nsc, nbi, OUTF);
}